// Round 1
// baseline (395.301 us; speedup 1.0000x reference)
//
#include <hip/hip_runtime.h>
#include <stdint.h>

// ---------------- workspace layout (float elements) ----------------
// scalars:
//  [0..3]    w absmax bits (atomic, q/k/v/p)
//  [4..7]    w_sf          [8..11] b_sf
//  [16..33]  head absmax bits (mat m in {q,k,v} * 6 heads)
//  [40..45] qh_sf  [46..51] kh_sf  [52..57] vh_sf
//  [64..69] sf  [70..75] x0_int  [76..81] bpoly  [82..87] c_int
//  [88..93] exp_sf  [94..99] s16  [100..105] 30*x0
#define WS_SCALAR 0
#define WS_WT     1024
#define WS_BI     (1024 + 4*147456)          // 590848
#define WS_QBUF   (WS_BI + 1536)             // 592384
#define NROW      8192
#define NE        (NROW*384)                 // 3145728
#define WS_ABUF   (WS_QBUF + 3*NE)
// total floats: WS_ABUF + NE = 13,175,296  (~52.7 MB of ws)

__global__ __launch_bounds__(256) void k_init(float* ws) {
    if (threadIdx.x < 128) ws[threadIdx.x] = 0.0f;
}

__device__ __forceinline__ float blockmax_and_get(float lmax, float* red) {
    #pragma unroll
    for (int off = 32; off; off >>= 1) lmax = fmaxf(lmax, __shfl_xor(lmax, off, 64));
    int wv = threadIdx.x >> 6, ln = threadIdx.x & 63;
    if (ln == 0) red[wv] = lmax;
    __syncthreads();
    return fmaxf(fmaxf(red[0], red[1]), fmaxf(red[2], red[3]));
}

__global__ __launch_bounds__(256) void k_wmax(const float* __restrict__ w0, const float* __restrict__ w1,
                                              const float* __restrict__ w2, const float* __restrict__ w3,
                                              float* ws) {
    int m = blockIdx.x / 36, chunk = blockIdx.x % 36;
    const float* w = (m == 0) ? w0 : (m == 1) ? w1 : (m == 2) ? w2 : w3;
    int base = chunk * 4096 + threadIdx.x;
    float lmax = 0.f;
    #pragma unroll
    for (int i = 0; i < 16; i++) lmax = fmaxf(lmax, fabsf(w[base + i*256]));
    __shared__ float red[4];
    float m4 = blockmax_and_get(lmax, red);
    if (threadIdx.x == 0) atomicMax((unsigned int*)&ws[m], __float_as_uint(m4));
}

// quantize weights (stored TRANSPOSED: wT[i][o]) and biases; publish w_sf/b_sf
__global__ __launch_bounds__(256) void k_wquant(const float* __restrict__ w0, const float* __restrict__ w1,
                                                const float* __restrict__ w2, const float* __restrict__ w3,
                                                const float* __restrict__ b0, const float* __restrict__ b1,
                                                const float* __restrict__ b2, const float* __restrict__ b3,
                                                const float* __restrict__ xsf, float* ws) {
    const unsigned* wu = (const unsigned*)ws;
    if (blockIdx.x < 576) {
        int m = blockIdx.x / 144, chunk = blockIdx.x % 144;
        const float* w = (m == 0) ? w0 : (m == 1) ? w1 : (m == 2) ? w2 : w3;
        float s = fmaxf(__uint_as_float(wu[m]), 1e-8f) / 127.0f;
        float* wt = ws + WS_WT + m * 147456;
        int base = chunk * 1024 + threadIdx.x;
        #pragma unroll
        for (int i = 0; i < 4; i++) {
            int e = base + i * 256;
            int o = e / 384, ii = e - o * 384;
            float q = fminf(fmaxf(rintf(w[e] / s), -128.f), 127.f);
            wt[ii * 384 + o] = q;
        }
    } else {
        for (int idx = threadIdx.x; idx < 1536; idx += 256) {
            int m = idx / 384, o = idx - m * 384;
            const float* b = (m == 0) ? b0 : (m == 1) ? b1 : (m == 2) ? b2 : b3;
            float s = fmaxf(__uint_as_float(wu[m]), 1e-8f) / 127.0f;
            float bsf = (m < 3) ? __fmul_rn(s, xsf[0]) : __fmul_rn(s, 0.00390625f);
            float bq = fminf(fmaxf(rintf(b[o] / bsf), -2147483648.0f), 2147483648.0f);
            ws[WS_BI + m * 384 + o] = bq;
            if (o == 0) { ws[4 + m] = s; ws[8 + m] = bsf; }
        }
    }
}

// 64x64 tile fp32 SGEMM: out = (X_int @ wT + b_int) * b_sf
// QKV: X_int = x/x_sf, 18 n-tiles (3 mats x 6 heads), per-head absmax epilogue
// final: X_int = attn buffer as-is (algebraically exact pv), out -> d_out (+out_sf)
template<bool QKV>
__global__ __launch_bounds__(256) void k_gemm(const float* __restrict__ X,
                                              const float* __restrict__ ws,
                                              const float* __restrict__ xsf,
                                              float* __restrict__ out_base,
                                              float* ws_mut) {
    int mtile = blockIdx.x, ntile = blockIdx.y;
    int mat = QKV ? (ntile / 6) : 3;
    int nb  = QKV ? ((ntile % 6) * 64) : (ntile * 64);
    const float* wT = ws + WS_WT + mat * 147456;
    const float* bi = ws + WS_BI + mat * 384;
    float bsf = ws[8 + mat];
    float xs = QKV ? xsf[0] : 1.0f;
    float* out = QKV ? (out_base + mat * NE) : out_base;

    __shared__ float As[16][68];
    __shared__ float Bs[16][68];
    __shared__ float red[4];
    int tid = threadIdx.x, tx = tid & 15, ty = tid >> 4;
    int m0 = mtile * 64;
    float acc[4][4] = {};

    for (int k0 = 0; k0 < 384; k0 += 16) {
        #pragma unroll
        for (int i = 0; i < 4; i++) {
            int f = tid + 256 * i;
            int m = f >> 4, k = f & 15;
            float v = X[(m0 + m) * 384 + k0 + k];
            if (QKV) v = v / xs;              // IEEE div, matches ref x/x_sf
            As[k][m] = v;
        }
        #pragma unroll
        for (int i = 0; i < 4; i++) {
            int f = tid + 256 * i;
            int n = f & 63, k = f >> 6;
            Bs[k][n] = wT[(k0 + k) * 384 + nb + n];
        }
        __syncthreads();
        #pragma unroll
        for (int k = 0; k < 16; k++) {
            float4 av = *(const float4*)&As[k][ty * 4];
            float4 bv = *(const float4*)&Bs[k][tx * 4];
            float a[4] = {av.x, av.y, av.z, av.w};
            float b[4] = {bv.x, bv.y, bv.z, bv.w};
            #pragma unroll
            for (int i = 0; i < 4; i++)
                #pragma unroll
                for (int j = 0; j < 4; j++) acc[i][j] += a[i] * b[j];
        }
        __syncthreads();
    }

    float lmax = 0.f;
    #pragma unroll
    for (int i = 0; i < 4; i++) {
        int row = m0 + ty * 4 + i;
        float vv[4];
        #pragma unroll
        for (int j = 0; j < 4; j++) {
            int col = nb + tx * 4 + j;
            float v = __fmul_rn(__fadd_rn(acc[i][j], bi[col]), bsf);
            vv[j] = v;
            lmax = fmaxf(lmax, fabsf(v));
        }
        *(float4*)&out[row * 384 + nb + tx * 4] = make_float4(vv[0], vv[1], vv[2], vv[3]);
    }
    if (QKV) {
        __syncthreads();
        float m4 = blockmax_and_get(lmax, red);
        if (tid == 0)
            atomicMax((unsigned int*)&ws_mut[16 + mat * 6 + (nb >> 6)], __float_as_uint(m4));
    } else {
        if (mtile == 0 && ntile == 0 && tid == 0) out[NE] = bsf;  // out_sf = wp_sf*(1/256)
    }
}

// derive per-head scales + int-softmax constants (s16 is analytic: head max = c_int*2^30)
__global__ void k_scales(float* ws) {
    int h = threadIdx.x;
    if (h >= 6) return;
    const unsigned* wu = (const unsigned*)ws;
    float qsf = fmaxf(__uint_as_float(wu[16 + 0 * 6 + h]), 1e-8f) / 127.0f;
    float ksf = fmaxf(__uint_as_float(wu[16 + 1 * 6 + h]), 1e-8f) / 127.0f;
    float vsf = fmaxf(__uint_as_float(wu[16 + 2 * 6 + h]), 1e-8f) / 127.0f;
    float sf = __fmul_rn(ksf, qsf);                 // ref: wei_sf = kh_sf * qh_sf
    const float X0f = -0.6931f;
    const float C0f = 0.35815147f;
    const float C1f = (float)(0.96963238 / 0.35815147);
    const float C2f = (float)(1.0 / 0.35815147);
    float x0i   = floorf(X0f / sf);
    float bpoly = floorf(C1f / sf);
    float sfsq  = __fmul_rn(sf, sf);
    float cint  = floorf(C2f / sfsq);
    float psf   = __fmul_rn(C0f, sfsq);
    float expsf = psf / 1073741824.0f;              // exact (2^30)
    float rawmax = __fmul_rn(cint, 1073741824.0f);  // exact scaling
    float s16 = fmaxf(__fmul_rn(rawmax, expsf), 1e-8f) / 32767.0f;
    float thirty = __fmul_rn(30.0f, x0i);
    ws[40+h]=qsf; ws[46+h]=ksf; ws[52+h]=vsf; ws[64+h]=sf; ws[70+h]=x0i;
    ws[76+h]=bpoly; ws[82+h]=cint; ws[88+h]=expsf; ws[94+h]=s16; ws[100+h]=thirty;
}

// fused attention: block = (b,h,row-quarter); 4 waves x 16 rows
__global__ __launch_bounds__(256) void k_attn(const float* __restrict__ qb,
                                              const float* __restrict__ kb,
                                              const float* __restrict__ vb,
                                              const float* __restrict__ ws,
                                              float* __restrict__ ab) {
    int qblock = blockIdx.x & 3;
    int bh = blockIdx.x >> 2;
    int b = bh / 6, h = bh - (bh / 6) * 6;
    float qsf = ws[40+h], ksf = ws[46+h], vsf = ws[52+h];
    float sf = ws[64+h], x0i = ws[70+h], bpoly = ws[76+h], cint = ws[82+h];
    float expsf = ws[88+h], s16 = ws[94+h], thirty = ws[100+h];

    __shared__ signed char s_kT[64][260];   // kT[d][j], padded: conflict-free reads/writes
    __shared__ signed char s_v[256][68];    // v[j][d]
    __shared__ float s_w[4][256];
    __shared__ float s_q[4][64];

    int tid = threadIdx.x;
    // stage + quantize K,V (int8), float4 global reads
    for (int i = 0; i < 16; i++) {
        int f = i * 256 + tid;
        int j = f >> 4;
        int d4 = (f & 15) * 4;
        int gbase = (b * 256 + j) * 384 + h * 64 + d4;
        float4 kv = *(const float4*)&kb[gbase];
        float4 vv = *(const float4*)&vb[gbase];
        int ki0 = (int)fminf(fmaxf(rintf(kv.x / ksf), -128.f), 127.f);
        int ki1 = (int)fminf(fmaxf(rintf(kv.y / ksf), -128.f), 127.f);
        int ki2 = (int)fminf(fmaxf(rintf(kv.z / ksf), -128.f), 127.f);
        int ki3 = (int)fminf(fmaxf(rintf(kv.w / ksf), -128.f), 127.f);
        s_kT[d4+0][j] = (signed char)ki0;
        s_kT[d4+1][j] = (signed char)ki1;
        s_kT[d4+2][j] = (signed char)ki2;
        s_kT[d4+3][j] = (signed char)ki3;
        int vi0 = (int)fminf(fmaxf(rintf(vv.x / vsf), -128.f), 127.f);
        int vi1 = (int)fminf(fmaxf(rintf(vv.y / vsf), -128.f), 127.f);
        int vi2 = (int)fminf(fmaxf(rintf(vv.z / vsf), -128.f), 127.f);
        int vi3 = (int)fminf(fmaxf(rintf(vv.w / vsf), -128.f), 127.f);
        unsigned pack = (unsigned)(vi0 & 255) | ((unsigned)(vi1 & 255) << 8) |
                        ((unsigned)(vi2 & 255) << 16) | ((unsigned)(vi3 & 255) << 24);
        *(unsigned*)&s_v[j][d4] = pack;
    }
    __syncthreads();

    int wv = tid >> 6, lane = tid & 63;
    for (int rr = 0; rr < 16; rr++) {
        int row = qblock * 64 + wv * 16 + rr;
        // stage quantized q row (lane = d)
        float qv = qb[(b * 256 + row) * 384 + h * 64 + lane];
        s_q[wv][lane] = fminf(fmaxf(rintf(qv / qsf), -128.f), 127.f);
        __syncthreads();

        // scores: 4 causal columns per lane, exact int8 dot in fp32
        int j0 = lane * 4;
        float sc[4] = {0.f, 0.f, 0.f, 0.f};
        if (j0 <= row) {
            for (int d = 0; d < 64; d++) {
                float qd = s_q[wv][d];
                unsigned kw = *(const unsigned*)&s_kT[d][j0];
                sc[0] += qd * (float)(signed char)(kw & 255);
                sc[1] += qd * (float)(signed char)((kw >> 8) & 255);
                sc[2] += qd * (float)(signed char)((kw >> 16) & 255);
                sc[3] += qd * (float)(signed char)(kw >> 24);
            }
        }
        float xi[4];
        float lmax = -__builtin_inff();
        #pragma unroll
        for (int c = 0; c < 4; c++) {
            float wei = __fmul_rn(__fmul_rn(__fmul_rn(sc[c], qsf), ksf), 0.125f);
            xi[c] = wei / sf;
            if (j0 + c <= row) lmax = fmaxf(lmax, xi[c]);
        }
        #pragma unroll
        for (int off = 32; off; off >>= 1) lmax = fmaxf(lmax, __shfl_xor(lmax, off, 64));

        // int_exp + 16-bit requant (s16 analytic); masked cols are exactly 0
        float eint[4];
        float lsum = 0.f;
        #pragma unroll
        for (int c = 0; c < 4; c++) {
            eint[c] = 0.f;
            if (j0 + c <= row) {
                float xsv = fmaxf(__fsub_rn(xi[c], lmax), thirty);
                float qf = floorf(xsv / x0i);
                float r = __fsub_rn(xsv, __fmul_rn(x0i, qf));
                float z = __fadd_rn(__fmul_rn(__fadd_rn(r, bpoly), r), cint);
                float p2 = ldexpf(1.0f, 30 - (int)qf);        // exact 2^(30-q)
                float eraw = fmaxf(floorf(__fmul_rn(z, p2)), 0.0f);
                float esc = __fmul_rn(eraw, expsf);
                float q16 = fminf(fmaxf(rintf(esc / s16), -32768.f), 32767.f);
                float e = __fmul_rn(q16, s16);
                eint[c] = e / s16;                            // ref's (q*s)/s dance
            }
            lsum += eint[c];
        }
        #pragma unroll
        for (int off = 32; off; off >>= 1) lsum += __shfl_xor(lsum, off, 64);
        float factor = floorf(4294967296.0f / lsum);
        #pragma unroll
        for (int c = 0; c < 4; c++) {
            float wf = 0.f;
            if (j0 + c <= row)
                wf = floorf(__fmul_rn(__fmul_rn(eint[c], factor), 5.9604644775390625e-08f)); // *2^-24 exact
            s_w[wv][j0 + c] = wf;
        }
        __syncthreads();

        // PV: lane = d; wfin (0..256 int) x v_int exact in fp32
        float ipv = 0.f;
        for (int j = 0; j <= row; j++)
            ipv += s_w[wv][j] * (float)s_v[j][lane];
        // pv = (ipv * vh_sf) / 256 ; (the ref's *1/256 then /net_sf cancels exactly)
        float outv = __fmul_rn(__fmul_rn(ipv, vsf), 0.00390625f);
        ab[(b * 256 + row) * 384 + h * 64 + lane] = outv;
    }
}

extern "C" void kernel_launch(void* const* d_in, const int* in_sizes, int n_in,
                              void* d_out, int out_size, void* d_ws, size_t ws_size,
                              hipStream_t stream) {
    const float* x   = (const float*)d_in[0];
    const float* xsf = (const float*)d_in[1];
    const float* Wq  = (const float*)d_in[2];
    const float* bq  = (const float*)d_in[3];
    const float* Wk  = (const float*)d_in[4];
    const float* bk  = (const float*)d_in[5];
    const float* Wv  = (const float*)d_in[6];
    const float* bv  = (const float*)d_in[7];
    const float* Wp  = (const float*)d_in[8];
    const float* bp  = (const float*)d_in[9];
    float* ws  = (float*)d_ws;
    float* out = (float*)d_out;
    float* qkv = ws + WS_QBUF;
    float* ab  = ws + WS_ABUF;

    k_init<<<1, 256, 0, stream>>>(ws);
    k_wmax<<<144, 256, 0, stream>>>(Wq, Wk, Wv, Wp, ws);
    k_wquant<<<577, 256, 0, stream>>>(Wq, Wk, Wv, Wp, bq, bk, bv, bp, xsf, ws);
    k_gemm<true><<<dim3(128, 18), 256, 0, stream>>>(x, ws, xsf, qkv, ws);
    k_scales<<<1, 64, 0, stream>>>(ws);
    k_attn<<<768, 256, 0, stream>>>(qkv, qkv + NE, qkv + 2 * NE, ws, ab);
    k_gemm<false><<<dim3(128, 6), 256, 0, stream>>>(ab, ws, xsf, out, ws);
}

// Round 2
// 279.818 us; speedup vs baseline: 1.4127x; 1.4127x over previous
//
#include <hip/hip_runtime.h>
#include <stdint.h>

// ---------------- workspace layout (float elements) ----------------
//  [0..3]  w absmax bits   [4..7] w_sf   [8..11] b_sf
//  [16..33] head absmax bits (q/k/v * 6 heads)
//  [40..45] qh_sf [46..51] kh_sf [52..57] vh_sf
//  [64..69] sf [70..75] x0_int [76..81] bpoly [82..87] c_int
//  [88..93] exp_sf [94..99] s16 [100..105] 30*x0
#define WS_WT     1024
#define WS_BI     (1024 + 4*147456)          // 590848
#define WS_QBUF   (WS_BI + 1536)             // 592384
#define NROW      8192
#define NE        (NROW*384)                 // 3145728
#define WS_C8     (WS_QBUF + 3*NE)           // compact: q8 (NE B) + k8 (NE B) + vf (2*NE B) = NE floats
// total floats: WS_C8 + NE = 13,175,296 (~52.7 MB) — same as round 1

typedef __attribute__((ext_vector_type(4))) int      i32x4;
typedef __attribute__((ext_vector_type(4))) float    f32x4;
typedef __attribute__((ext_vector_type(8))) _Float16 f16x8;

__global__ __launch_bounds__(256) void k_init(float* ws) {
    if (threadIdx.x < 128) ws[threadIdx.x] = 0.0f;
}

__device__ __forceinline__ float blockmax_and_get(float lmax, float* red) {
    #pragma unroll
    for (int off = 32; off; off >>= 1) lmax = fmaxf(lmax, __shfl_xor(lmax, off, 64));
    int wv = threadIdx.x >> 6, ln = threadIdx.x & 63;
    if (ln == 0) red[wv] = lmax;
    __syncthreads();
    return fmaxf(fmaxf(red[0], red[1]), fmaxf(red[2], red[3]));
}

__global__ __launch_bounds__(256) void k_wmax(const float* __restrict__ w0, const float* __restrict__ w1,
                                              const float* __restrict__ w2, const float* __restrict__ w3,
                                              float* ws) {
    int m = blockIdx.x / 36, chunk = blockIdx.x % 36;
    const float* w = (m == 0) ? w0 : (m == 1) ? w1 : (m == 2) ? w2 : w3;
    int base = chunk * 4096 + threadIdx.x;
    float lmax = 0.f;
    #pragma unroll
    for (int i = 0; i < 16; i++) lmax = fmaxf(lmax, fabsf(w[base + i*256]));
    __shared__ float red[4];
    float m4 = blockmax_and_get(lmax, red);
    if (threadIdx.x == 0) atomicMax((unsigned int*)&ws[m], __float_as_uint(m4));
}

__global__ __launch_bounds__(256) void k_wquant(const float* __restrict__ w0, const float* __restrict__ w1,
                                                const float* __restrict__ w2, const float* __restrict__ w3,
                                                const float* __restrict__ b0, const float* __restrict__ b1,
                                                const float* __restrict__ b2, const float* __restrict__ b3,
                                                const float* __restrict__ xsf, float* ws) {
    const unsigned* wu = (const unsigned*)ws;
    if (blockIdx.x < 576) {
        int m = blockIdx.x / 144, chunk = blockIdx.x % 144;
        const float* w = (m == 0) ? w0 : (m == 1) ? w1 : (m == 2) ? w2 : w3;
        float s = fmaxf(__uint_as_float(wu[m]), 1e-8f) / 127.0f;
        float* wt = ws + WS_WT + m * 147456;
        int base = chunk * 1024 + threadIdx.x;
        #pragma unroll
        for (int i = 0; i < 4; i++) {
            int e = base + i * 256;
            int o = e / 384, ii = e - o * 384;
            float q = fminf(fmaxf(rintf(w[e] / s), -128.f), 127.f);
            wt[ii * 384 + o] = q;
        }
    } else {
        for (int idx = threadIdx.x; idx < 1536; idx += 256) {
            int m = idx / 384, o = idx - m * 384;
            const float* b = (m == 0) ? b0 : (m == 1) ? b1 : (m == 2) ? b2 : b3;
            float s = fmaxf(__uint_as_float(wu[m]), 1e-8f) / 127.0f;
            float bsf = (m < 3) ? __fmul_rn(s, xsf[0]) : __fmul_rn(s, 0.00390625f);
            float bq = fminf(fmaxf(rintf(b[o] / bsf), -2147483648.0f), 2147483648.0f);
            ws[WS_BI + m * 384 + o] = bq;
            if (o == 0) { ws[4 + m] = s; ws[8 + m] = bsf; }
        }
    }
}

template<bool QKV>
__global__ __launch_bounds__(256) void k_gemm(const float* __restrict__ X,
                                              const float* __restrict__ ws,
                                              const float* __restrict__ xsf,
                                              float* __restrict__ out_base,
                                              float* ws_mut) {
    int mtile = blockIdx.x, ntile = blockIdx.y;
    int mat = QKV ? (ntile / 6) : 3;
    int nb  = QKV ? ((ntile % 6) * 64) : (ntile * 64);
    const float* wT = ws + WS_WT + mat * 147456;
    const float* bi = ws + WS_BI + mat * 384;
    float bsf = ws[8 + mat];
    float xs = QKV ? xsf[0] : 1.0f;
    float* out = QKV ? (out_base + mat * NE) : out_base;

    __shared__ float As[16][68];
    __shared__ float Bs[16][68];
    __shared__ float red[4];
    int tid = threadIdx.x, tx = tid & 15, ty = tid >> 4;
    int m0 = mtile * 64;
    float acc[4][4] = {};

    for (int k0 = 0; k0 < 384; k0 += 16) {
        #pragma unroll
        for (int i = 0; i < 4; i++) {
            int f = tid + 256 * i;
            int m = f >> 4, k = f & 15;
            float v = X[(m0 + m) * 384 + k0 + k];
            if (QKV) v = v / xs;
            As[k][m] = v;
        }
        #pragma unroll
        for (int i = 0; i < 4; i++) {
            int f = tid + 256 * i;
            int n = f & 63, k = f >> 6;
            Bs[k][n] = wT[(k0 + k) * 384 + nb + n];
        }
        __syncthreads();
        #pragma unroll
        for (int k = 0; k < 16; k++) {
            float4 av = *(const float4*)&As[k][ty * 4];
            float4 bv = *(const float4*)&Bs[k][tx * 4];
            float a[4] = {av.x, av.y, av.z, av.w};
            float b[4] = {bv.x, bv.y, bv.z, bv.w};
            #pragma unroll
            for (int i = 0; i < 4; i++)
                #pragma unroll
                for (int j = 0; j < 4; j++) acc[i][j] += a[i] * b[j];
        }
        __syncthreads();
    }

    float lmax = 0.f;
    #pragma unroll
    for (int i = 0; i < 4; i++) {
        int row = m0 + ty * 4 + i;
        float vv[4];
        #pragma unroll
        for (int j = 0; j < 4; j++) {
            int col = nb + tx * 4 + j;
            float v = __fmul_rn(__fadd_rn(acc[i][j], bi[col]), bsf);
            vv[j] = v;
            lmax = fmaxf(lmax, fabsf(v));
        }
        *(float4*)&out[row * 384 + nb + tx * 4] = make_float4(vv[0], vv[1], vv[2], vv[3]);
    }
    if (QKV) {
        __syncthreads();
        float m4 = blockmax_and_get(lmax, red);
        if (tid == 0)
            atomicMax((unsigned int*)&ws_mut[16 + mat * 6 + (nb >> 6)], __float_as_uint(m4));
    } else {
        if (mtile == 0 && ntile == 0 && tid == 0) out[NE] = bsf;
    }
}

__global__ void k_scales(float* ws) {
    int h = threadIdx.x;
    if (h >= 6) return;
    const unsigned* wu = (const unsigned*)ws;
    float qsf = fmaxf(__uint_as_float(wu[16 + 0 * 6 + h]), 1e-8f) / 127.0f;
    float ksf = fmaxf(__uint_as_float(wu[16 + 1 * 6 + h]), 1e-8f) / 127.0f;
    float vsf = fmaxf(__uint_as_float(wu[16 + 2 * 6 + h]), 1e-8f) / 127.0f;
    float sf = __fmul_rn(ksf, qsf);
    const float X0f = -0.6931f;
    const float C0f = 0.35815147f;
    const float C1f = (float)(0.96963238 / 0.35815147);
    const float C2f = (float)(1.0 / 0.35815147);
    float x0i   = floorf(X0f / sf);
    float bpoly = floorf(C1f / sf);
    float sfsq  = __fmul_rn(sf, sf);
    float cint  = floorf(C2f / sfsq);
    float psf   = __fmul_rn(C0f, sfsq);
    float expsf = psf / 1073741824.0f;
    float rawmax = __fmul_rn(cint, 1073741824.0f);
    float s16 = fmaxf(__fmul_rn(rawmax, expsf), 1e-8f) / 32767.0f;
    float thirty = __fmul_rn(30.0f, x0i);
    ws[40+h]=qsf; ws[46+h]=ksf; ws[52+h]=vsf; ws[64+h]=sf; ws[70+h]=x0i;
    ws[76+h]=bpoly; ws[82+h]=cint; ws[88+h]=expsf; ws[94+h]=s16; ws[100+h]=thirty;
}

__device__ __forceinline__ unsigned short f16bits(float x) {
    _Float16 h = (_Float16)x;
    unsigned short u;
    __builtin_memcpy(&u, &h, 2);
    return u;
}

// quantize q/k -> int8 row-major [8192][384]; v -> f16 in B-fragment-swizzled order
// vf element: [((bh*8 + kv>>5)*4 + d>>4)*512 + (((kv>>3)&3)*16 + (d&15))*8 + (kv&7)]
__global__ __launch_bounds__(256) void k_prequant(const float* __restrict__ qb,
                                                  const float* __restrict__ kb,
                                                  const float* __restrict__ vb,
                                                  const float* __restrict__ ws,
                                                  char* __restrict__ q8,
                                                  char* __restrict__ k8,
                                                  unsigned short* __restrict__ vf) {
    int sec = blockIdx.x / 3072;
    int id = (blockIdx.x % 3072) * 256 + threadIdx.x;
    if (sec < 2) {
        const float* src = sec ? kb : qb;
        const float* sfb = ws + (sec ? 46 : 40);
        int row = id / 96, c4 = (id % 96) * 4;
        float s = sfb[c4 >> 6];
        float4 v = *(const float4*)&src[row * 384 + c4];
        int a0 = (int)fminf(fmaxf(rintf(v.x / s), -128.f), 127.f);
        int a1 = (int)fminf(fmaxf(rintf(v.y / s), -128.f), 127.f);
        int a2 = (int)fminf(fmaxf(rintf(v.z / s), -128.f), 127.f);
        int a3 = (int)fminf(fmaxf(rintf(v.w / s), -128.f), 127.f);
        unsigned pk = (unsigned)(a0 & 255) | ((unsigned)(a1 & 255) << 8) |
                      ((unsigned)(a2 & 255) << 16) | ((unsigned)(a3 & 255) << 24);
        ((unsigned*)(sec ? k8 : q8))[id] = pk;
    } else {
        int d = id & 63;
        int rest = id >> 6;
        int kvg = rest & 63;
        int bh = rest >> 6;              // 0..191
        int b = bh / 6, h = bh - (bh / 6) * 6;
        float s = ws[52 + h];
        int kv0 = kvg * 4;
        unsigned pk01, pk23;
        {
            float v0 = vb[(b * 256 + kv0 + 0) * 384 + h * 64 + d];
            float v1 = vb[(b * 256 + kv0 + 1) * 384 + h * 64 + d];
            float v2 = vb[(b * 256 + kv0 + 2) * 384 + h * 64 + d];
            float v3 = vb[(b * 256 + kv0 + 3) * 384 + h * 64 + d];
            unsigned short u0 = f16bits(fminf(fmaxf(rintf(v0 / s), -128.f), 127.f));
            unsigned short u1 = f16bits(fminf(fmaxf(rintf(v1 / s), -128.f), 127.f));
            unsigned short u2 = f16bits(fminf(fmaxf(rintf(v2 / s), -128.f), 127.f));
            unsigned short u3 = f16bits(fminf(fmaxf(rintf(v3 / s), -128.f), 127.f));
            pk01 = (unsigned)u0 | ((unsigned)u1 << 16);
            pk23 = (unsigned)u2 | ((unsigned)u3 << 16);
        }
        int c = kv0 >> 5, quad = (kv0 >> 3) & 3, j0 = kv0 & 7;
        int base = ((bh * 8 + c) * 4 + (d >> 4)) * 512 + (quad * 16 + (d & 15)) * 8 + j0;
        uint2 pk = make_uint2(pk01, pk23);
        *(uint2*)&vf[base] = pk;     // j0 in {0,4} -> 8B aligned
    }
}

// fused MFMA attention: block = (b,h,qt); wave = 16 q-rows; no __syncthreads
__global__ __launch_bounds__(256) void k_attn(const char* __restrict__ q8,
                                              const char* __restrict__ k8,
                                              const unsigned short* __restrict__ vf,
                                              const float* __restrict__ ws,
                                              float* __restrict__ ab) {
    __shared__ _Float16 pS[4][64][8];   // wave-private P transpose scratch (4 KB)
    int qt = blockIdx.x & 3, bh = blockIdx.x >> 2;
    int b = bh / 6, h = bh - (bh / 6) * 6;
    float qsf = ws[40+h], ksf = ws[46+h], vsf = ws[52+h];
    float sf = ws[64+h], x0i = ws[70+h], bpoly = ws[76+h], cint = ws[82+h];
    float expsf = ws[88+h], s16 = ws[94+h], thirty = ws[100+h];

    int tid = threadIdx.x, w = tid >> 6, lane = tid & 63;
    int quad = lane >> 4, l15 = lane & 15;
    int strip0 = qt * 64 + w * 16;
    int ntiles = (strip0 >> 4) + 1;

    // Q A-fragment straight from global (row = strip0 + l15, k = quad*16..+16)
    const i32x4 afrag = *(const i32x4*)(q8 + (b * 256 + strip0 + l15) * 384 + h * 64 + quad * 16);

    // scores -> xi (x_int units), per lane: element (row=quad*4+r, col=ct*16+l15)
    f32x4 xi[16];
    i32x4 zero4 = {0, 0, 0, 0};
    #pragma unroll
    for (int ct = 0; ct < 16; ct++) {
        if (ct < ntiles) {
            i32x4 bfrag = *(const i32x4*)(k8 + (b * 256 + ct * 16 + l15) * 384 + h * 64 + quad * 16);
            i32x4 c = __builtin_amdgcn_mfma_i32_16x16x64_i8(afrag, bfrag, zero4, 0, 0, 0);
            #pragma unroll
            for (int r = 0; r < 4; r++) {
                float wei = __fmul_rn(__fmul_rn(__fmul_rn((float)c[r], qsf), ksf), 0.125f);
                xi[ct][r] = wei / sf;
            }
        }
    }

    // per-row max (rows live across the 16 lanes sharing `quad`)
    float NI = -__builtin_inff();
    f32x4 m = {NI, NI, NI, NI};
    #pragma unroll
    for (int ct = 0; ct < 16; ct++) {
        if (ct < ntiles) {
            bool last = (ct == ntiles - 1);
            #pragma unroll
            for (int r = 0; r < 4; r++)
                if (!last || (l15 <= quad * 4 + r)) m[r] = fmaxf(m[r], xi[ct][r]);
        }
    }
    #pragma unroll
    for (int o = 8; o; o >>= 1) {
        m.x = fmaxf(m.x, __shfl_xor(m.x, o));
        m.y = fmaxf(m.y, __shfl_xor(m.y, o));
        m.z = fmaxf(m.z, __shfl_xor(m.z, o));
        m.w = fmaxf(m.w, __shfl_xor(m.w, o));
    }

    // int_exp + 16-bit requant (element-wise identical to round-1 formula)
    f32x4 sum = {0.f, 0.f, 0.f, 0.f};
    #pragma unroll
    for (int ct = 0; ct < 16; ct++) {
        if (ct < ntiles) {
            bool last = (ct == ntiles - 1);
            #pragma unroll
            for (int r = 0; r < 4; r++) {
                float ei = 0.f;
                if (!last || (l15 <= quad * 4 + r)) {
                    float xsv = fmaxf(__fsub_rn(xi[ct][r], m[r]), thirty);
                    float qf = floorf(xsv / x0i);
                    float rr = __fsub_rn(xsv, __fmul_rn(x0i, qf));
                    float z = __fadd_rn(__fmul_rn(__fadd_rn(rr, bpoly), rr), cint);
                    float p2 = ldexpf(1.0f, 30 - (int)qf);
                    float eraw = fmaxf(floorf(__fmul_rn(z, p2)), 0.0f);
                    float esc = __fmul_rn(eraw, expsf);
                    float q16 = fminf(fmaxf(rintf(esc / s16), -32768.f), 32767.f);
                    float e = __fmul_rn(q16, s16);
                    ei = e / s16;
                }
                xi[ct][r] = ei;
                sum[r] += ei;
            }
        }
    }
    #pragma unroll
    for (int o = 8; o; o >>= 1) {
        sum.x += __shfl_xor(sum.x, o);
        sum.y += __shfl_xor(sum.y, o);
        sum.z += __shfl_xor(sum.z, o);
        sum.w += __shfl_xor(sum.w, o);
    }
    f32x4 fac;
    #pragma unroll
    for (int r = 0; r < 4; r++) fac[r] = floorf(4294967296.0f / sum[r]);

    // wfin (in place); zero for tiles beyond the strip
    #pragma unroll
    for (int ct = 0; ct < 16; ct++) {
        #pragma unroll
        for (int r = 0; r < 4; r++) {
            if (ct < ntiles)
                xi[ct][r] = floorf(__fmul_rn(__fmul_rn(xi[ct][r], fac[r]), 5.9604644775390625e-08f));
            else
                xi[ct][r] = 0.f;
        }
    }

    // PV: per 32-col chunk, C-layout -> A-layout via wave-private LDS, then f16 MFMA
    f32x4 o0 = {0,0,0,0}, o1 = {0,0,0,0}, o2 = {0,0,0,0}, o3 = {0,0,0,0};
    int nch = (ntiles + 1) >> 1;
    #pragma unroll
    for (int c = 0; c < 8; c++) {
        if (c < nch) {
            #pragma unroll
            for (int t2 = 0; t2 < 2; t2++) {
                int qd = t2 * 2 + (l15 >> 3);
                #pragma unroll
                for (int r = 0; r < 4; r++)
                    pS[w][qd * 16 + quad * 4 + r][l15 & 7] = (_Float16)xi[2 * c + t2][r];
            }
            f16x8 pa = *(f16x8*)&pS[w][lane][0];
            int vbase = ((bh * 8 + c) * 4) * 512 + lane * 8;
            f16x8 vb0 = *(const f16x8*)&vf[vbase];
            f16x8 vb1 = *(const f16x8*)&vf[vbase + 512];
            f16x8 vb2 = *(const f16x8*)&vf[vbase + 1024];
            f16x8 vb3 = *(const f16x8*)&vf[vbase + 1536];
            o0 = __builtin_amdgcn_mfma_f32_16x16x32_f16(pa, vb0, o0, 0, 0, 0);
            o1 = __builtin_amdgcn_mfma_f32_16x16x32_f16(pa, vb1, o1, 0, 0, 0);
            o2 = __builtin_amdgcn_mfma_f32_16x16x32_f16(pa, vb2, o2, 0, 0, 0);
            o3 = __builtin_amdgcn_mfma_f32_16x16x32_f16(pa, vb3, o3, 0, 0, 0);
        }
    }

    // epilogue: C layout (row=quad*4+r, col=nt*16+l15); out = ipv*vsf/256
    float* outp = ab + (b * 256 + strip0 + quad * 4) * 384 + h * 64 + l15;
    #pragma unroll
    for (int r = 0; r < 4; r++) {
        outp[r * 384 +  0] = __fmul_rn(__fmul_rn(o0[r], vsf), 0.00390625f);
        outp[r * 384 + 16] = __fmul_rn(__fmul_rn(o1[r], vsf), 0.00390625f);
        outp[r * 384 + 32] = __fmul_rn(__fmul_rn(o2[r], vsf), 0.00390625f);
        outp[r * 384 + 48] = __fmul_rn(__fmul_rn(o3[r], vsf), 0.00390625f);
    }
}

extern "C" void kernel_launch(void* const* d_in, const int* in_sizes, int n_in,
                              void* d_out, int out_size, void* d_ws, size_t ws_size,
                              hipStream_t stream) {
    const float* x   = (const float*)d_in[0];
    const float* xsf = (const float*)d_in[1];
    const float* Wq  = (const float*)d_in[2];
    const float* bq  = (const float*)d_in[3];
    const float* Wk  = (const float*)d_in[4];
    const float* bk  = (const float*)d_in[5];
    const float* Wv  = (const float*)d_in[6];
    const float* bv  = (const float*)d_in[7];
    const float* Wp  = (const float*)d_in[8];
    const float* bp  = (const float*)d_in[9];
    float* ws  = (float*)d_ws;
    float* out = (float*)d_out;
    float* qkv = ws + WS_QBUF;
    char*  q8  = (char*)(ws + WS_C8);
    char*  k8  = q8 + NE;
    unsigned short* vfp = (unsigned short*)(k8 + NE);
    float* ab  = ws + WS_QBUF;   // reuse q-fp32 region (dead after k_prequant)

    k_init<<<1, 256, 0, stream>>>(ws);
    k_wmax<<<144, 256, 0, stream>>>(Wq, Wk, Wv, Wp, ws);
    k_wquant<<<577, 256, 0, stream>>>(Wq, Wk, Wv, Wp, bq, bk, bv, bp, xsf, ws);
    k_gemm<true><<<dim3(128, 18), 256, 0, stream>>>(x, ws, xsf, qkv, ws);
    k_scales<<<1, 64, 0, stream>>>(ws);
    k_prequant<<<9216, 256, 0, stream>>>(qkv, qkv + NE, qkv + 2 * NE, ws, q8, k8, vfp);
    k_attn<<<768, 256, 0, stream>>>(q8, k8, vfp, ws, ab);
    k_gemm<false><<<dim3(128, 6), 256, 0, stream>>>(ab, ws, xsf, out, ws);
}

// Round 3
// 226.726 us; speedup vs baseline: 1.7435x; 1.2342x over previous
//
#include <hip/hip_runtime.h>
#include <stdint.h>

// ---------------- workspace layout (float elements) ----------------
//  [0..3]  w absmax bits   [4..7] w_sf   [8..11] b_sf
//  [16..33] head absmax bits (q/k/v * 6 heads)
//  [40..45] qh_sf [46..51] kh_sf [52..57] vh_sf
//  [64..69] sf [70..75] x0_int [76..81] bpoly [82..87] c_int
//  [88..93] exp_sf [94..99] s16 [100..105] 30*x0
#define WS_WT     1024                        // w16 frag-order: 4 mats * 147456 ushort
#define WS_BI     (1024 + 4*147456)           // 590848 (float b_int)
#define WS_QBUF   (WS_BI + 1536)              // 592384: qkv fp32 (3*NE); later ab + abplanes
#define NROW      8192
#define NE        (NROW*384)                  // 3145728
#define WS_C8     (WS_QBUF + 3*NE)            // xplanes (2*NE ushort) then q8/k8/vf
// total floats: WS_C8 + NE = 13,175,296 (~52.7 MB)

typedef __attribute__((ext_vector_type(4))) int      i32x4;
typedef __attribute__((ext_vector_type(4))) float    f32x4;
typedef __attribute__((ext_vector_type(8))) _Float16 f16x8;

__global__ __launch_bounds__(256) void k_init(float* ws) {
    if (threadIdx.x < 128) ws[threadIdx.x] = 0.0f;
}

__device__ __forceinline__ float blockmax_and_get(float lmax, float* red) {
    #pragma unroll
    for (int off = 32; off; off >>= 1) lmax = fmaxf(lmax, __shfl_xor(lmax, off, 64));
    int wv = threadIdx.x >> 6, ln = threadIdx.x & 63;
    if (ln == 0) red[wv] = lmax;
    __syncthreads();
    return fmaxf(fmaxf(red[0], red[1]), fmaxf(red[2], red[3]));
}

__global__ __launch_bounds__(256) void k_wmax(const float* __restrict__ w0, const float* __restrict__ w1,
                                              const float* __restrict__ w2, const float* __restrict__ w3,
                                              float* ws) {
    int m = blockIdx.x / 36, chunk = blockIdx.x % 36;
    const float* w = (m == 0) ? w0 : (m == 1) ? w1 : (m == 2) ? w2 : w3;
    int base = chunk * 4096 + threadIdx.x;
    float lmax = 0.f;
    #pragma unroll
    for (int i = 0; i < 16; i++) lmax = fmaxf(lmax, fabsf(w[base + i*256]));
    __shared__ float red[4];
    float m4 = blockmax_and_get(lmax, red);
    if (threadIdx.x == 0) atomicMax((unsigned int*)&ws[m], __float_as_uint(m4));
}

// quantize weights -> f16 (exact, int8 range) in MFMA B-fragment order; biases fp32
// w16 idx (per mat): ((o/16)*12 + k/32)*512 + (((k%32)/8)*16 + o%16)*8 + k%8
__global__ __launch_bounds__(256) void k_wquant(const float* __restrict__ w0, const float* __restrict__ w1,
                                                const float* __restrict__ w2, const float* __restrict__ w3,
                                                const float* __restrict__ b0, const float* __restrict__ b1,
                                                const float* __restrict__ b2, const float* __restrict__ b3,
                                                const float* __restrict__ xsf, float* ws) {
    const unsigned* wu = (const unsigned*)ws;
    if (blockIdx.x < 576) {
        int m = blockIdx.x / 144, chunk = blockIdx.x % 144;
        const float* w = (m == 0) ? w0 : (m == 1) ? w1 : (m == 2) ? w2 : w3;
        float s = fmaxf(__uint_as_float(wu[m]), 1e-8f) / 127.0f;
        unsigned short* wt16 = (unsigned short*)(ws + WS_WT) + m * 147456;
        int base = chunk * 1024 + threadIdx.x;
        #pragma unroll
        for (int i = 0; i < 4; i++) {
            int e = base + i * 256;
            int o = e / 384, k = e - o * 384;   // o = out col, k = in dim
            float q = fminf(fmaxf(rintf(w[e] / s), -128.f), 127.f);
            _Float16 qh = (_Float16)q;
            unsigned short qb;
            __builtin_memcpy(&qb, &qh, 2);
            int idx = ((o >> 4) * 12 + (k >> 5)) * 512 + ((((k & 31) >> 3) << 4) + (o & 15)) * 8 + (k & 7);
            wt16[idx] = qb;
        }
    } else {
        for (int idx = threadIdx.x; idx < 1536; idx += 256) {
            int m = idx / 384, o = idx - m * 384;
            const float* b = (m == 0) ? b0 : (m == 1) ? b1 : (m == 2) ? b2 : b3;
            float s = fmaxf(__uint_as_float(wu[m]), 1e-8f) / 127.0f;
            float bsf = (m < 3) ? __fmul_rn(s, xsf[0]) : __fmul_rn(s, 0.00390625f);
            float bq = fminf(fmaxf(rintf(b[o] / bsf), -2147483648.0f), 2147483648.0f);
            ws[WS_BI + m * 384 + o] = bq;
            if (o == 0) { ws[4 + m] = s; ws[8 + m] = bsf; }
        }
    }
}

// fp32 -> exact f16 hi/lo planes in MFMA A-fragment order
// plane idx: ((row/16)*12 + k/32)*512 + (((k%32)/8)*16 + row%16)*8 + k%8
template<bool DIV>
__global__ __launch_bounds__(256) void k_xsplit(const float* __restrict__ src,
                                                const float* __restrict__ xsf,
                                                unsigned short* __restrict__ hip_,
                                                unsigned short* __restrict__ lop_) {
    int gid = blockIdx.x * 256 + threadIdx.x;   // one float4
    int e0 = gid * 4;
    int row = e0 / 384, k = e0 - row * 384;
    float xs = DIV ? xsf[0] : 1.0f;
    float4 v = *(const float4*)&src[e0];
    float f[4] = {v.x, v.y, v.z, v.w};
    unsigned short hb[4], lb[4];
    #pragma unroll
    for (int i = 0; i < 4; i++) {
        float xi = DIV ? (f[i] / xs) : f[i];
        _Float16 h = (_Float16)xi;
        float hf = (float)h;
        _Float16 l = (_Float16)__fsub_rn(xi, hf);
        __builtin_memcpy(&hb[i], &h, 2);
        __builtin_memcpy(&lb[i], &l, 2);
    }
    int base = ((row >> 4) * 12 + (k >> 5)) * 512 + ((((k & 31) >> 3) << 4) + (row & 15)) * 8 + (k & 7);
    uint2 hp = make_uint2((unsigned)hb[0] | ((unsigned)hb[1] << 16),
                          (unsigned)hb[2] | ((unsigned)hb[3] << 16));
    uint2 lp = make_uint2((unsigned)lb[0] | ((unsigned)lb[1] << 16),
                          (unsigned)lb[2] | ((unsigned)lb[3] << 16));
    *(uint2*)(hip_ + base) = hp;
    *(uint2*)(lop_ + base) = lp;
}

// barrier-free MFMA GEMM: out = (Xf32 @ wT + b_int)*b_sf via f16x2-split A
// block = 128x128 tile (4 waves x 64x64); all frag loads coalesced dwordx4
template<bool QKV>
__global__ __launch_bounds__(256) void k_gemm16(const unsigned short* __restrict__ xhi,
                                                const unsigned short* __restrict__ xlo,
                                                const float* __restrict__ ws,
                                                float* __restrict__ out_base,
                                                float* ws_mut) {
    int mtile = blockIdx.x, nt = blockIdx.y;
    int mat = QKV ? (nt / 3) : 3;
    int cb  = QKV ? ((nt % 3) * 128) : (nt * 128);
    const unsigned short* w16 = (const unsigned short*)(ws + WS_WT) + mat * 147456;
    const float* bi = ws + WS_BI + mat * 384;
    float bsf = ws[8 + mat];
    float* out = QKV ? (out_base + mat * NE) : out_base;

    int tid = threadIdx.x, w = tid >> 6, lane = tid & 63;
    int rowoff = (w & 1) * 64, coloff = (w >> 1) * 64;
    int rt0 = (mtile * 128 + rowoff) >> 4;   // global 16-rowtile base, +0..3
    int ct0 = (cb + coloff) >> 4;            // global 16-coltile base, +0..3

    const unsigned short* ah = xhi + rt0 * (12 * 512) + lane * 8;
    const unsigned short* al = xlo + rt0 * (12 * 512) + lane * 8;
    const unsigned short* bw = w16 + ct0 * (12 * 512) + lane * 8;

    f32x4 acc[4][4] = {};
    for (int k32 = 0; k32 < 12; k32++) {
        f16x8 bf[4];
        #pragma unroll
        for (int ct = 0; ct < 4; ct++)
            bf[ct] = *(const f16x8*)(bw + (ct * 12 + k32) * 512);
        #pragma unroll
        for (int rt = 0; rt < 4; rt++) {
            f16x8 hi = *(const f16x8*)(ah + (rt * 12 + k32) * 512);
            f16x8 lo = *(const f16x8*)(al + (rt * 12 + k32) * 512);
            #pragma unroll
            for (int ct = 0; ct < 4; ct++) {
                acc[rt][ct] = __builtin_amdgcn_mfma_f32_16x16x32_f16(lo, bf[ct], acc[rt][ct], 0, 0, 0);
                acc[rt][ct] = __builtin_amdgcn_mfma_f32_16x16x32_f16(hi, bf[ct], acc[rt][ct], 0, 0, 0);
            }
        }
    }

    int quad = lane >> 4, l15 = lane & 15;
    float bcol[4];
    #pragma unroll
    for (int ct = 0; ct < 4; ct++) bcol[ct] = bi[(ct0 + ct) * 16 + l15];

    float lmax = 0.f;
    #pragma unroll
    for (int rt = 0; rt < 4; rt++) {
        #pragma unroll
        for (int r = 0; r < 4; r++) {
            int row = (rt0 + rt) * 16 + quad * 4 + r;
            #pragma unroll
            for (int ct = 0; ct < 4; ct++) {
                int col = (ct0 + ct) * 16 + l15;
                float v = __fmul_rn(__fadd_rn(acc[rt][ct][r], bcol[ct]), bsf);
                lmax = fmaxf(lmax, fabsf(v));
                out[row * 384 + col] = v;
            }
        }
    }
    if (QKV) {
        #pragma unroll
        for (int off = 32; off; off >>= 1) lmax = fmaxf(lmax, __shfl_xor(lmax, off, 64));
        if (lane == 0)
            atomicMax((unsigned int*)&ws_mut[16 + mat * 6 + (ct0 >> 2)], __float_as_uint(lmax));
    } else {
        if (mtile == 0 && nt == 0 && tid == 0) out[NE] = bsf;   // out_sf
    }
}

__global__ void k_scales(float* ws) {
    int h = threadIdx.x;
    if (h >= 6) return;
    const unsigned* wu = (const unsigned*)ws;
    float qsf = fmaxf(__uint_as_float(wu[16 + 0 * 6 + h]), 1e-8f) / 127.0f;
    float ksf = fmaxf(__uint_as_float(wu[16 + 1 * 6 + h]), 1e-8f) / 127.0f;
    float vsf = fmaxf(__uint_as_float(wu[16 + 2 * 6 + h]), 1e-8f) / 127.0f;
    float sf = __fmul_rn(ksf, qsf);
    const float X0f = -0.6931f;
    const float C0f = 0.35815147f;
    const float C1f = (float)(0.96963238 / 0.35815147);
    const float C2f = (float)(1.0 / 0.35815147);
    float x0i   = floorf(X0f / sf);
    float bpoly = floorf(C1f / sf);
    float sfsq  = __fmul_rn(sf, sf);
    float cint  = floorf(C2f / sfsq);
    float psf   = __fmul_rn(C0f, sfsq);
    float expsf = psf / 1073741824.0f;
    float rawmax = __fmul_rn(cint, 1073741824.0f);
    float s16 = fmaxf(__fmul_rn(rawmax, expsf), 1e-8f) / 32767.0f;
    float thirty = __fmul_rn(30.0f, x0i);
    ws[40+h]=qsf; ws[46+h]=ksf; ws[52+h]=vsf; ws[64+h]=sf; ws[70+h]=x0i;
    ws[76+h]=bpoly; ws[82+h]=cint; ws[88+h]=expsf; ws[94+h]=s16; ws[100+h]=thirty;
}

__device__ __forceinline__ unsigned short f16bits(float x) {
    _Float16 h = (_Float16)x;
    unsigned short u;
    __builtin_memcpy(&u, &h, 2);
    return u;
}

// quantize q/k -> int8 row-major; v -> f16 in B-fragment-swizzled order
__global__ __launch_bounds__(256) void k_prequant(const float* __restrict__ qb,
                                                  const float* __restrict__ kb,
                                                  const float* __restrict__ vb,
                                                  const float* __restrict__ ws,
                                                  char* __restrict__ q8,
                                                  char* __restrict__ k8,
                                                  unsigned short* __restrict__ vf) {
    int sec = blockIdx.x / 3072;
    int id = (blockIdx.x % 3072) * 256 + threadIdx.x;
    if (sec < 2) {
        const float* src = sec ? kb : qb;
        const float* sfb = ws + (sec ? 46 : 40);
        int row = id / 96, c4 = (id % 96) * 4;
        float s = sfb[c4 >> 6];
        float4 v = *(const float4*)&src[row * 384 + c4];
        int a0 = (int)fminf(fmaxf(rintf(v.x / s), -128.f), 127.f);
        int a1 = (int)fminf(fmaxf(rintf(v.y / s), -128.f), 127.f);
        int a2 = (int)fminf(fmaxf(rintf(v.z / s), -128.f), 127.f);
        int a3 = (int)fminf(fmaxf(rintf(v.w / s), -128.f), 127.f);
        unsigned pk = (unsigned)(a0 & 255) | ((unsigned)(a1 & 255) << 8) |
                      ((unsigned)(a2 & 255) << 16) | ((unsigned)(a3 & 255) << 24);
        ((unsigned*)(sec ? k8 : q8))[id] = pk;
    } else {
        int d = id & 63;
        int rest = id >> 6;
        int kvg = rest & 63;
        int bh = rest >> 6;
        int b = bh / 6, h = bh - (bh / 6) * 6;
        float s = ws[52 + h];
        int kv0 = kvg * 4;
        unsigned pk01, pk23;
        {
            float v0 = vb[(b * 256 + kv0 + 0) * 384 + h * 64 + d];
            float v1 = vb[(b * 256 + kv0 + 1) * 384 + h * 64 + d];
            float v2 = vb[(b * 256 + kv0 + 2) * 384 + h * 64 + d];
            float v3 = vb[(b * 256 + kv0 + 3) * 384 + h * 64 + d];
            unsigned short u0 = f16bits(fminf(fmaxf(rintf(v0 / s), -128.f), 127.f));
            unsigned short u1 = f16bits(fminf(fmaxf(rintf(v1 / s), -128.f), 127.f));
            unsigned short u2 = f16bits(fminf(fmaxf(rintf(v2 / s), -128.f), 127.f));
            unsigned short u3 = f16bits(fminf(fmaxf(rintf(v3 / s), -128.f), 127.f));
            pk01 = (unsigned)u0 | ((unsigned)u1 << 16);
            pk23 = (unsigned)u2 | ((unsigned)u3 << 16);
        }
        int c = kv0 >> 5, quad = (kv0 >> 3) & 3, j0 = kv0 & 7;
        int base = ((bh * 8 + c) * 4 + (d >> 4)) * 512 + (quad * 16 + (d & 15)) * 8 + j0;
        uint2 pk = make_uint2(pk01, pk23);
        *(uint2*)&vf[base] = pk;
    }
}

// fused MFMA attention (unchanged from round 2)
__global__ __launch_bounds__(256) void k_attn(const char* __restrict__ q8,
                                              const char* __restrict__ k8,
                                              const unsigned short* __restrict__ vf,
                                              const float* __restrict__ ws,
                                              float* __restrict__ ab) {
    __shared__ _Float16 pS[4][64][8];
    int qt = blockIdx.x & 3, bh = blockIdx.x >> 2;
    int b = bh / 6, h = bh - (bh / 6) * 6;
    float qsf = ws[40+h], ksf = ws[46+h], vsf = ws[52+h];
    float sf = ws[64+h], x0i = ws[70+h], bpoly = ws[76+h], cint = ws[82+h];
    float expsf = ws[88+h], s16 = ws[94+h], thirty = ws[100+h];

    int tid = threadIdx.x, w = tid >> 6, lane = tid & 63;
    int quad = lane >> 4, l15 = lane & 15;
    int strip0 = qt * 64 + w * 16;
    int ntiles = (strip0 >> 4) + 1;

    const i32x4 afrag = *(const i32x4*)(q8 + (b * 256 + strip0 + l15) * 384 + h * 64 + quad * 16);

    f32x4 xi[16];
    i32x4 zero4 = {0, 0, 0, 0};
    #pragma unroll
    for (int ct = 0; ct < 16; ct++) {
        if (ct < ntiles) {
            i32x4 bfrag = *(const i32x4*)(k8 + (b * 256 + ct * 16 + l15) * 384 + h * 64 + quad * 16);
            i32x4 c = __builtin_amdgcn_mfma_i32_16x16x64_i8(afrag, bfrag, zero4, 0, 0, 0);
            #pragma unroll
            for (int r = 0; r < 4; r++) {
                float wei = __fmul_rn(__fmul_rn(__fmul_rn((float)c[r], qsf), ksf), 0.125f);
                xi[ct][r] = wei / sf;
            }
        }
    }

    float NI = -__builtin_inff();
    f32x4 m = {NI, NI, NI, NI};
    #pragma unroll
    for (int ct = 0; ct < 16; ct++) {
        if (ct < ntiles) {
            bool last = (ct == ntiles - 1);
            #pragma unroll
            for (int r = 0; r < 4; r++)
                if (!last || (l15 <= quad * 4 + r)) m[r] = fmaxf(m[r], xi[ct][r]);
        }
    }
    #pragma unroll
    for (int o = 8; o; o >>= 1) {
        m.x = fmaxf(m.x, __shfl_xor(m.x, o));
        m.y = fmaxf(m.y, __shfl_xor(m.y, o));
        m.z = fmaxf(m.z, __shfl_xor(m.z, o));
        m.w = fmaxf(m.w, __shfl_xor(m.w, o));
    }

    f32x4 sum = {0.f, 0.f, 0.f, 0.f};
    #pragma unroll
    for (int ct = 0; ct < 16; ct++) {
        if (ct < ntiles) {
            bool last = (ct == ntiles - 1);
            #pragma unroll
            for (int r = 0; r < 4; r++) {
                float ei = 0.f;
                if (!last || (l15 <= quad * 4 + r)) {
                    float xsv = fmaxf(__fsub_rn(xi[ct][r], m[r]), thirty);
                    float qf = floorf(xsv / x0i);
                    float rr = __fsub_rn(xsv, __fmul_rn(x0i, qf));
                    float z = __fadd_rn(__fmul_rn(__fadd_rn(rr, bpoly), rr), cint);
                    float p2 = ldexpf(1.0f, 30 - (int)qf);
                    float eraw = fmaxf(floorf(__fmul_rn(z, p2)), 0.0f);
                    float esc = __fmul_rn(eraw, expsf);
                    float q16 = fminf(fmaxf(rintf(esc / s16), -32768.f), 32767.f);
                    float e = __fmul_rn(q16, s16);
                    ei = e / s16;
                }
                xi[ct][r] = ei;
                sum[r] += ei;
            }
        }
    }
    #pragma unroll
    for (int o = 8; o; o >>= 1) {
        sum.x += __shfl_xor(sum.x, o);
        sum.y += __shfl_xor(sum.y, o);
        sum.z += __shfl_xor(sum.z, o);
        sum.w += __shfl_xor(sum.w, o);
    }
    f32x4 fac;
    #pragma unroll
    for (int r = 0; r < 4; r++) fac[r] = floorf(4294967296.0f / sum[r]);

    #pragma unroll
    for (int ct = 0; ct < 16; ct++) {
        #pragma unroll
        for (int r = 0; r < 4; r++) {
            if (ct < ntiles)
                xi[ct][r] = floorf(__fmul_rn(__fmul_rn(xi[ct][r], fac[r]), 5.9604644775390625e-08f));
            else
                xi[ct][r] = 0.f;
        }
    }

    f32x4 o0 = {0,0,0,0}, o1 = {0,0,0,0}, o2 = {0,0,0,0}, o3 = {0,0,0,0};
    int nch = (ntiles + 1) >> 1;
    #pragma unroll
    for (int c = 0; c < 8; c++) {
        if (c < nch) {
            #pragma unroll
            for (int t2 = 0; t2 < 2; t2++) {
                int qd = t2 * 2 + (l15 >> 3);
                #pragma unroll
                for (int r = 0; r < 4; r++)
                    pS[w][qd * 16 + quad * 4 + r][l15 & 7] = (_Float16)xi[2 * c + t2][r];
            }
            f16x8 pa = *(f16x8*)&pS[w][lane][0];
            int vbase = ((bh * 8 + c) * 4) * 512 + lane * 8;
            f16x8 vb0 = *(const f16x8*)&vf[vbase];
            f16x8 vb1 = *(const f16x8*)&vf[vbase + 512];
            f16x8 vb2 = *(const f16x8*)&vf[vbase + 1024];
            f16x8 vb3 = *(const f16x8*)&vf[vbase + 1536];
            o0 = __builtin_amdgcn_mfma_f32_16x16x32_f16(pa, vb0, o0, 0, 0, 0);
            o1 = __builtin_amdgcn_mfma_f32_16x16x32_f16(pa, vb1, o1, 0, 0, 0);
            o2 = __builtin_amdgcn_mfma_f32_16x16x32_f16(pa, vb2, o2, 0, 0, 0);
            o3 = __builtin_amdgcn_mfma_f32_16x16x32_f16(pa, vb3, o3, 0, 0, 0);
        }
    }

    float* outp = ab + (b * 256 + strip0 + quad * 4) * 384 + h * 64 + l15;
    #pragma unroll
    for (int r = 0; r < 4; r++) {
        outp[r * 384 +  0] = __fmul_rn(__fmul_rn(o0[r], vsf), 0.00390625f);
        outp[r * 384 + 16] = __fmul_rn(__fmul_rn(o1[r], vsf), 0.00390625f);
        outp[r * 384 + 32] = __fmul_rn(__fmul_rn(o2[r], vsf), 0.00390625f);
        outp[r * 384 + 48] = __fmul_rn(__fmul_rn(o3[r], vsf), 0.00390625f);
    }
}

extern "C" void kernel_launch(void* const* d_in, const int* in_sizes, int n_in,
                              void* d_out, int out_size, void* d_ws, size_t ws_size,
                              hipStream_t stream) {
    const float* x   = (const float*)d_in[0];
    const float* xsf = (const float*)d_in[1];
    const float* Wq  = (const float*)d_in[2];
    const float* bq  = (const float*)d_in[3];
    const float* Wk  = (const float*)d_in[4];
    const float* bk  = (const float*)d_in[5];
    const float* Wv  = (const float*)d_in[6];
    const float* bv  = (const float*)d_in[7];
    const float* Wp  = (const float*)d_in[8];
    const float* bp  = (const float*)d_in[9];
    float* ws  = (float*)d_ws;
    float* out = (float*)d_out;
    float* qkv = ws + WS_QBUF;

    // xplanes live in WS_C8 until k_prequant overwrites it
    unsigned short* xhi = (unsigned short*)(ws + WS_C8);
    unsigned short* xlo = xhi + NE;
    // q8/k8/vf (after gemm) also in WS_C8
    char*  q8  = (char*)(ws + WS_C8);
    char*  k8  = q8 + NE;
    unsigned short* vfp = (unsigned short*)(k8 + NE);
    // ab fp32 reuses q-plane; ab split planes reuse k-plane (dead after prequant)
    float* ab  = ws + WS_QBUF;
    unsigned short* abhi = (unsigned short*)(ws + WS_QBUF + NE);
    unsigned short* ablo = abhi + NE;

    k_init<<<1, 256, 0, stream>>>(ws);
    k_wmax<<<144, 256, 0, stream>>>(Wq, Wk, Wv, Wp, ws);
    k_wquant<<<577, 256, 0, stream>>>(Wq, Wk, Wv, Wp, bq, bk, bv, bp, xsf, ws);
    k_xsplit<true><<<3072, 256, 0, stream>>>(x, xsf, xhi, xlo);
    k_gemm16<true><<<dim3(64, 9), 256, 0, stream>>>(xhi, xlo, ws, qkv, ws);
    k_scales<<<1, 64, 0, stream>>>(ws);
    k_prequant<<<9216, 256, 0, stream>>>(qkv, qkv + NE, qkv + 2 * NE, ws, q8, k8, vfp);
    k_attn<<<768, 256, 0, stream>>>(q8, k8, vfp, ws, ab);
    k_xsplit<false><<<3072, 256, 0, stream>>>(ab, xsf, abhi, ablo);
    k_gemm16<false><<<dim3(64, 3), 256, 0, stream>>>(abhi, ablo, ws, out, ws);
}